// Round 4
// baseline (1603.209 us; speedup 1.0000x reference)
//
#include <hip/hip_runtime.h>
#include <hip/hip_bf16.h>

#define BB 128
#define TT 25
#define VOCAB 10000
#define HIDD 512

typedef __hip_bfloat16 bf16;
typedef short bf16x8 __attribute__((ext_vector_type(8)));
typedef float f32x4 __attribute__((ext_vector_type(4)));

__device__ __forceinline__ float sigmoidf_(float x) { return 1.0f / (1.0f + __expf(-x)); }

__device__ __forceinline__ float4 f4_fma(float s, float4 w, float4 a) {
    a.x += s * w.x; a.y += s * w.y; a.z += s * w.z; a.w += s * w.w;
    return a;
}

__device__ __forceinline__ unsigned short f2bfu(float x) {
    bf16 h = __float2bfloat16(x);
    return *reinterpret_cast<unsigned short*>(&h);
}

// =====================================================================
// h0 path (unchanged)
// =====================================================================
__device__ __forceinline__ float4 core128(const float* __restrict__ Wp,
                                          const float* __restrict__ arow)
{
    float4 acc = {0.f, 0.f, 0.f, 0.f};
    #pragma unroll 2
    for (int k = 0; k < 128; k += 8) {
        float4 w[8];
        #pragma unroll
        for (int j = 0; j < 8; ++j)
            w[j] = *(const float4*)(Wp + (size_t)(k + j) * 512);
        #pragma unroll
        for (int j = 0; j < 8; ++j)
            acc = f4_fma(arow[k + j], w[j], acc);
    }
    return acc;
}

#define PHASE_REDUCE(SVAR) \
    __syncthreads(); \
    float4 SVAR; \
    if (tid < 32) { \
        SVAR = red[tid]; \
        _Pragma("unroll") \
        for (int j = 1; j < 8; ++j) { \
            float4 p = red[tid + 32 * j]; \
            SVAR.x += p.x; SVAR.y += p.y; SVAR.z += p.z; SVAR.w += p.w; \
        } \
    }

// vgg[128,4096] @ W_in[4096,512], K split over 4 blocks (z). grid (8,64,4)
__global__ __launch_bounds__(256) void k_h0p(const float* __restrict__ A,
                                             const float* __restrict__ W,
                                             float* __restrict__ partial)
{
    __shared__ float As2[2][1032];
    __shared__ float4 red[256];
    const int tid = threadIdx.x;
    const int n4 = tid & 15, mi = (tid >> 4) & 1, kh = tid >> 5;
    const int m0 = blockIdx.y * 2, col0 = blockIdx.x * 64, kq = blockIdx.z;

    #pragma unroll
    for (int l = 0; l < 2; ++l) {
        int idx = tid + l * 256;
        int r = idx >> 8, c4 = (idx & 255) * 4;
        *(float4*)&As2[r][c4] =
            *(const float4*)&A[(size_t)(m0 + r) * 4096 + kq * 1024 + c4];
    }
    __syncthreads();
    red[tid] = core128(W + (size_t)(kq * 1024 + kh * 128) * 512 + col0 + n4 * 4,
                       &As2[mi][kh * 128]);
    PHASE_REDUCE(s)
    if (tid < 32) {
        int m = m0 + (tid >> 4), cc = col0 + (tid & 15) * 4;
        *(float4*)&partial[((size_t)kq * 128 + m) * 512 + cc] = s;
    }
}

// finalize: sum 4 partials + bias, tanh, write row-major h0/h1
__global__ void k_h0f(const float* __restrict__ partial,
                      const float* __restrict__ bias,
                      float* __restrict__ s0, float* __restrict__ s1)
{
    int i = blockIdx.x * 256 + threadIdx.x;
    size_t e = (size_t)i * 4;
    int cc = (int)(e & 511);
    float4 s = *(const float4*)&partial[e];
    #pragma unroll
    for (int j = 1; j < 4; ++j) {
        float4 p = *(const float4*)&partial[(size_t)j * 128 * 512 + e];
        s.x += p.x; s.y += p.y; s.z += p.z; s.w += p.w;
    }
    float4 b4 = *(const float4*)&bias[cc];
    float4 o;
    o.x = tanhf(s.x + b4.x); o.y = tanhf(s.y + b4.y);
    o.z = tanhf(s.z + b4.z); o.w = tanhf(s.w + b4.w);
    *(float4*)&s0[e] = o;
    *(float4*)&s1[e] = o;
}

// =====================================================================
// x-projection precompute setup
// =====================================================================
// emb gather -> bf16 xbf[3200][512]  (row = t*128 + b)
__global__ __launch_bounds__(256) void k_xbf(const int* __restrict__ toks,
                                             const float* __restrict__ emb,
                                             unsigned short* __restrict__ xbf)
{
    int i = (blockIdx.x * 256 + threadIdx.x) * 4;   // over 3200*512
    int row = i >> 9, col = i & 511;
    int b = row & 127, tt = row >> 7;
    int tok = toks[b * TT + tt];
    float4 v = *(const float4*)&emb[(size_t)tok * 512 + col];
    ushort4 u;
    u.x = f2bfu(v.x); u.y = f2bfu(v.y); u.z = f2bfu(v.z); u.w = f2bfu(v.w);
    *(ushort4*)&xbf[(size_t)row * 512 + col] = u;
}

// x-half (rows 0..511) of Wu0/Wr0/Wc0 -> transposed bf16 wxT[1536][512]
__global__ __launch_bounds__(256) void k_wxT3(const float* __restrict__ Wu,
                                              const float* __restrict__ Wr,
                                              const float* __restrict__ Wc,
                                              unsigned short* __restrict__ wxT)
{
    __shared__ float T[32][33];
    const int tid = threadIdx.x;
    const int n0 = blockIdx.x * 32, k0 = blockIdx.y * 32, g = blockIdx.z;
    const float* W = g == 0 ? Wu : g == 1 ? Wr : Wc;
    {
        int r = tid >> 3, c4 = (tid & 7) * 4;
        float4 v = *(const float4*)&W[(size_t)(k0 + r) * 512 + n0 + c4];
        T[r][c4 + 0] = v.x; T[r][c4 + 1] = v.y; T[r][c4 + 2] = v.z; T[r][c4 + 3] = v.w;
    }
    __syncthreads();
    {
        int rn = tid >> 3, c4 = (tid & 7) * 4;
        ushort4 u;
        u.x = f2bfu(T[c4 + 0][rn]);
        u.y = f2bfu(T[c4 + 1][rn]);
        u.z = f2bfu(T[c4 + 2][rn]);
        u.w = f2bfu(T[c4 + 3][rn]);
        *(ushort4*)&wxT[(size_t)(g * 512 + n0 + rn) * 512 + k0 + c4] = u;
    }
}

// pre[3200][1536] = xbf @ wxT^T  (MFMA bf16, fp32 out). grid (12, 25)
__global__ __launch_bounds__(256) void k_pre(const unsigned short* __restrict__ A,
                                             const unsigned short* __restrict__ Bt,
                                             float* __restrict__ out)
{
    __shared__ unsigned short As16[128][40];
    __shared__ unsigned short Bs16[128][40];
    const int tid = threadIdx.x;
    const int lane = tid & 63, w = tid >> 6;
    const int quad = lane >> 4, l15 = lane & 15;
    const int n0 = blockIdx.x * 128, m0 = blockIdx.y * 128;

    f32x4 acc[8][2];
    #pragma unroll
    for (int i = 0; i < 8; ++i)
        #pragma unroll
        for (int j = 0; j < 2; ++j) acc[i][j] = (f32x4){0.f, 0.f, 0.f, 0.f};

    ushort4 pa[4], pb[4];
    #pragma unroll
    for (int l = 0; l < 4; ++l) {
        int idx = tid + l * 256;
        int r = idx >> 3, c8 = (idx & 7) * 4;
        pa[l] = *(const ushort4*)&A[(size_t)(m0 + r) * 512 + c8];
        pb[l] = *(const ushort4*)&Bt[(size_t)(n0 + r) * 512 + c8];
    }

    for (int k0 = 0; k0 < 512; k0 += 32) {
        #pragma unroll
        for (int l = 0; l < 4; ++l) {
            int idx = tid + l * 256;
            int r = idx >> 3, c8 = (idx & 7) * 4;
            *(ushort4*)&As16[r][c8] = pa[l];
            *(ushort4*)&Bs16[r][c8] = pb[l];
        }
        if (k0 + 32 < 512) {
            #pragma unroll
            for (int l = 0; l < 4; ++l) {
                int idx = tid + l * 256;
                int r = idx >> 3, c8 = (idx & 7) * 4;
                pa[l] = *(const ushort4*)&A[(size_t)(m0 + r) * 512 + k0 + 32 + c8];
                pb[l] = *(const ushort4*)&Bt[(size_t)(n0 + r) * 512 + k0 + 32 + c8];
            }
        }
        __syncthreads();
        bf16x8 bfrag[2];
        #pragma unroll
        for (int nt = 0; nt < 2; ++nt)
            bfrag[nt] = *(const bf16x8*)&Bs16[w * 32 + nt * 16 + l15][quad * 8];
        #pragma unroll
        for (int mt = 0; mt < 8; ++mt) {
            bf16x8 afrag = *(const bf16x8*)&As16[mt * 16 + l15][quad * 8];
            acc[mt][0] = __builtin_amdgcn_mfma_f32_16x16x32_bf16(afrag, bfrag[0], acc[mt][0], 0, 0, 0);
            acc[mt][1] = __builtin_amdgcn_mfma_f32_16x16x32_bf16(afrag, bfrag[1], acc[mt][1], 0, 0, 0);
        }
        __syncthreads();
    }

    #pragma unroll
    for (int nt = 0; nt < 2; ++nt) {
        int n = n0 + w * 32 + nt * 16 + l15;
        #pragma unroll
        for (int mt = 0; mt < 8; ++mt) {
            #pragma unroll
            for (int r = 0; r < 4; ++r) {
                int m = m0 + mt * 16 + quad * 4 + r;
                __builtin_nontemporal_store(acc[mt][nt][r],
                                            &out[(size_t)m * 1536 + n]);
            }
        }
    }
}

// =====================================================================
// Gates kernel. grid 512 x 512thr. bx = mb(4b) | gate(2b) | cb(3b); XCD=cb.
// L0 gates (gu0,gr0): K=512 (h-half only; x-part folded from pre[]).
// L1 gates (gu1,gr1): K=1024 ([h0p;h1p]).
// Wave = 8 cols x 8 rows; 1 ds_read_b128 per 4-k (banks 0..31 exactly once).
// 8 waves K-split; LDS reduce. gr gates store gr*h.
// =====================================================================
__global__ __launch_bounds__(512, 4) void k_gates(
    const float* __restrict__ h0p, const float* __restrict__ h1p,
    const float* __restrict__ pre, int t,
    const float* __restrict__ Wu0, const float* __restrict__ bu0,
    const float* __restrict__ Wr0, const float* __restrict__ br0,
    const float* __restrict__ Wu1, const float* __restrict__ bu1,
    const float* __restrict__ Wr1, const float* __restrict__ br1,
    float* __restrict__ gu0, float* __restrict__ grh0,
    float* __restrict__ gu1, float* __restrict__ grh1,
    int doL0, int doL1)
{
    __shared__ float As[8 * 1028];
    __shared__ float4 red[8][8][16];
    const int bx = blockIdx.x;
    const int cb = bx & 7, gate = (bx >> 3) & 3, mb = bx >> 5;
    if (gate < 2) { if (!doL0) return; } else { if (!doL1) return; }
    const int col0 = cb * 64, m0 = mb * 8;
    const int tid = threadIdx.x;
    const int L0 = gate < 2;

    if (L0) {
        #pragma unroll
        for (int l = 0; l < 2; ++l) {
            int idx = tid + l * 512;
            int r = idx >> 7, c4 = (idx & 127) * 4;
            *(float4*)&As[r * 1028 + c4] =
                *(const float4*)&h0p[(size_t)(m0 + r) * 512 + c4];
        }
    } else {
        #pragma unroll
        for (int l = 0; l < 4; ++l) {
            int idx = tid + l * 512;
            int r2 = idx >> 7, c4 = (idx & 127) * 4;
            int r = r2 & 7, half = r2 >> 3;
            const float* src = half ? h1p : h0p;
            *(float4*)&As[r * 1028 + half * 512 + c4] =
                *(const float4*)&src[(size_t)(m0 + r) * 512 + c4];
        }
    }
    __syncthreads();

    {
        const int wv = tid >> 6, lane = tid & 63;
        const int r = lane >> 3, cg = lane & 7;
        const int Kw = L0 ? 64 : 128;
        const int nj = Kw >> 2;
        const float* W = gate == 0 ? Wu0 : gate == 1 ? Wr0 : gate == 2 ? Wu1 : Wr1;
        const int wrow0 = (L0 ? 512 : 0) + wv * Kw;
        const float* wp = W + (size_t)wrow0 * 512 + col0 + cg * 8;
        const float* ap = As + r * 1028 + wv * Kw;
        float4 aAa = {0,0,0,0}, aAb = {0,0,0,0};
        float4 aBa = {0,0,0,0}, aBb = {0,0,0,0};
        #pragma unroll 2
        for (int j = 0; j < nj; ++j) {
            float4 a4 = *(const float4*)(ap + j * 4);
            const float* wj = wp + (size_t)j * 2048;
            float4 w0a = *(const float4*)(wj);
            float4 w0b = *(const float4*)(wj + 4);
            float4 w1a = *(const float4*)(wj + 512);
            float4 w1b = *(const float4*)(wj + 516);
            float4 w2a = *(const float4*)(wj + 1024);
            float4 w2b = *(const float4*)(wj + 1028);
            float4 w3a = *(const float4*)(wj + 1536);
            float4 w3b = *(const float4*)(wj + 1540);
            aAa = f4_fma(a4.x, w0a, aAa); aAb = f4_fma(a4.x, w0b, aAb);
            aBa = f4_fma(a4.y, w1a, aBa); aBb = f4_fma(a4.y, w1b, aBb);
            aAa = f4_fma(a4.z, w2a, aAa); aAb = f4_fma(a4.z, w2b, aAb);
            aBa = f4_fma(a4.w, w3a, aBa); aBb = f4_fma(a4.w, w3b, aBb);
        }
        float4 sa, sb;
        sa.x = aAa.x + aBa.x; sa.y = aAa.y + aBa.y;
        sa.z = aAa.z + aBa.z; sa.w = aAa.w + aBa.w;
        sb.x = aAb.x + aBb.x; sb.y = aAb.y + aBb.y;
        sb.z = aAb.z + aBb.z; sb.w = aAb.w + aBb.w;
        red[wv][r][cg * 2]     = sa;
        red[wv][r][cg * 2 + 1] = sb;
    }
    __syncthreads();

    if (tid < 128) {
        const int row = tid >> 4, n4 = tid & 15;
        float4 s = red[0][row][n4];
        #pragma unroll
        for (int kq = 1; kq < 8; ++kq) {
            float4 p = red[kq][row][n4];
            s.x += p.x; s.y += p.y; s.z += p.z; s.w += p.w;
        }
        const int col = col0 + n4 * 4;
        const int m = m0 + row;
        if (L0) {
            float4 p4 = *(const float4*)&pre[((size_t)t * 128 + m) * 1536
                                             + gate * 512 + col];
            s.x += p4.x; s.y += p4.y; s.z += p4.z; s.w += p4.w;
        }
        const float* bias = gate == 0 ? bu0 : gate == 1 ? br0 : gate == 2 ? bu1 : br1;
        float4 b4 = *(const float4*)&bias[col];
        float4 o;
        o.x = sigmoidf_(s.x + b4.x); o.y = sigmoidf_(s.y + b4.y);
        o.z = sigmoidf_(s.z + b4.z); o.w = sigmoidf_(s.w + b4.w);
        size_t ofs = (size_t)m * 512 + col;
        if (gate == 1) {
            float4 h = *(const float4*)&h0p[ofs];
            o.x *= h.x; o.y *= h.y; o.z *= h.z; o.w *= h.w;
        } else if (gate == 3) {
            float4 h = *(const float4*)&h1p[ofs];
            o.x *= h.x; o.y *= h.y; o.z *= h.z; o.w *= h.w;
        }
        float* outp = gate == 0 ? gu0 : gate == 1 ? grh0 : gate == 2 ? gu1 : grh1;
        *(float4*)&outp[ofs] = o;
    }
}

// =====================================================================
// Cand+combine. grid 256 x 512thr. bx = mb(4b) | gate(1b) | cb(3b); XCD=cb.
// L0: hh0 = tanh(pre_c[t0] + grh0@Wc0h + bc0); K=512.
// L1: hh1 = tanh([h0p;grh1]@Wc1 + bc1); K=1024.
// =====================================================================
__global__ __launch_bounds__(512, 4) void k_cand(
    const float* __restrict__ h0p, const float* __restrict__ h1p,
    float* __restrict__ h0c, float* __restrict__ h1c,
    const float* __restrict__ pre, int t0, int t1,
    const float* __restrict__ Wc0, const float* __restrict__ bc0,
    const float* __restrict__ Wc1, const float* __restrict__ bc1,
    const float* __restrict__ gu0, const float* __restrict__ grh0,
    const float* __restrict__ gu1, const float* __restrict__ grh1,
    unsigned short* __restrict__ s1bf, float* __restrict__ outS,
    int doL0, int doL1)
{
    __shared__ float As[8 * 1028];
    __shared__ float4 red[8][8][16];
    const int bx = blockIdx.x;
    const int cb = bx & 7, gate = (bx >> 3) & 1, mb = bx >> 4;
    if (gate == 0) { if (!doL0) return; } else { if (!doL1) return; }
    const int col0 = cb * 64, m0 = mb * 8;
    const int tid = threadIdx.x;
    const int L0 = gate == 0;

    if (L0) {
        #pragma unroll
        for (int l = 0; l < 2; ++l) {
            int idx = tid + l * 512;
            int r = idx >> 7, c4 = (idx & 127) * 4;
            *(float4*)&As[r * 1028 + c4] =
                *(const float4*)&grh0[(size_t)(m0 + r) * 512 + c4];
        }
    } else {
        #pragma unroll
        for (int l = 0; l < 4; ++l) {
            int idx = tid + l * 512;
            int r2 = idx >> 7, c4 = (idx & 127) * 4;
            int r = r2 & 7, half = r2 >> 3;
            const float* src = half ? grh1 : h0p;
            *(float4*)&As[r * 1028 + half * 512 + c4] =
                *(const float4*)&src[(size_t)(m0 + r) * 512 + c4];
        }
    }
    __syncthreads();

    {
        const int wv = tid >> 6, lane = tid & 63;
        const int r = lane >> 3, cg = lane & 7;
        const int Kw = L0 ? 64 : 128;
        const int nj = Kw >> 2;
        const float* W = L0 ? Wc0 : Wc1;
        const int wrow0 = (L0 ? 512 : 0) + wv * Kw;
        const float* wp = W + (size_t)wrow0 * 512 + col0 + cg * 8;
        const float* ap = As + r * 1028 + wv * Kw;
        float4 aAa = {0,0,0,0}, aAb = {0,0,0,0};
        float4 aBa = {0,0,0,0}, aBb = {0,0,0,0};
        #pragma unroll 2
        for (int j = 0; j < nj; ++j) {
            float4 a4 = *(const float4*)(ap + j * 4);
            const float* wj = wp + (size_t)j * 2048;
            float4 w0a = *(const float4*)(wj);
            float4 w0b = *(const float4*)(wj + 4);
            float4 w1a = *(const float4*)(wj + 512);
            float4 w1b = *(const float4*)(wj + 516);
            float4 w2a = *(const float4*)(wj + 1024);
            float4 w2b = *(const float4*)(wj + 1028);
            float4 w3a = *(const float4*)(wj + 1536);
            float4 w3b = *(const float4*)(wj + 1540);
            aAa = f4_fma(a4.x, w0a, aAa); aAb = f4_fma(a4.x, w0b, aAb);
            aBa = f4_fma(a4.y, w1a, aBa); aBb = f4_fma(a4.y, w1b, aBb);
            aAa = f4_fma(a4.z, w2a, aAa); aAb = f4_fma(a4.z, w2b, aAb);
            aBa = f4_fma(a4.w, w3a, aBa); aBb = f4_fma(a4.w, w3b, aBb);
        }
        float4 sa, sb;
        sa.x = aAa.x + aBa.x; sa.y = aAa.y + aBa.y;
        sa.z = aAa.z + aBa.z; sa.w = aAa.w + aBa.w;
        sb.x = aAb.x + aBb.x; sb.y = aAb.y + aBb.y;
        sb.z = aAb.z + aBb.z; sb.w = aAb.w + aBb.w;
        red[wv][r][cg * 2]     = sa;
        red[wv][r][cg * 2 + 1] = sb;
    }
    __syncthreads();

    if (tid < 128) {
        const int row = tid >> 4, n4 = tid & 15;
        float4 s = red[0][row][n4];
        #pragma unroll
        for (int kq = 1; kq < 8; ++kq) {
            float4 p = red[kq][row][n4];
            s.x += p.x; s.y += p.y; s.z += p.z; s.w += p.w;
        }
        const int col = col0 + n4 * 4;
        const int m = m0 + row;
        if (L0) {
            float4 p4 = *(const float4*)&pre[((size_t)t0 * 128 + m) * 1536
                                             + 1024 + col];
            s.x += p4.x; s.y += p4.y; s.z += p4.z; s.w += p4.w;
        }
        const float* bias = L0 ? bc0 : bc1;
        float4 b4 = *(const float4*)&bias[col];
        size_t ofs = (size_t)m * 512 + col;
        float4 g  = *(const float4*)&((L0 ? gu0 : gu1)[ofs]);
        float4 hv = *(const float4*)&((L0 ? h0p : h1p)[ofs]);
        float4 o;
        o.x = g.x * hv.x + (1.f - g.x) * tanhf(s.x + b4.x);
        o.y = g.y * hv.y + (1.f - g.y) * tanhf(s.y + b4.y);
        o.z = g.z * hv.z + (1.f - g.z) * tanhf(s.z + b4.z);
        o.w = g.w * hv.w + (1.f - g.w) * tanhf(s.w + b4.w);
        *(float4*)&((L0 ? h0c : h1c)[ofs]) = o;
        if (!L0) {
            ushort4 u;
            u.x = f2bfu(o.x); u.y = f2bfu(o.y); u.z = f2bfu(o.z); u.w = f2bfu(o.w);
            *(ushort4*)&s1bf[(size_t)t1 * BB * HIDD + ofs] = u;
            if (t1 == TT - 1)
                *(float4*)&outS[(size_t)BB * HIDD + ofs] = o;
        } else if (t0 == TT - 1) {
            *(float4*)&outS[ofs] = o;
        }
    }
}

// =====================================================================
// Wout transpose+convert: fp32 [512][10000] -> bf16 [10000][512].
// =====================================================================
__global__ __launch_bounds__(256) void k_wT(const float* __restrict__ W,
                                            unsigned short* __restrict__ wT)
{
    __shared__ float T[32][33];
    const int tid = threadIdx.x;
    const int n0 = blockIdx.x * 32, k0 = blockIdx.y * 32;
    {
        int r = tid >> 3, c4 = (tid & 7) * 4;
        float4 v = {0.f, 0.f, 0.f, 0.f};
        if (n0 + c4 + 3 < VOCAB)
            v = *(const float4*)&W[(size_t)(k0 + r) * VOCAB + n0 + c4];
        else {
            if (n0 + c4 + 0 < VOCAB) v.x = W[(size_t)(k0 + r) * VOCAB + n0 + c4 + 0];
            if (n0 + c4 + 1 < VOCAB) v.y = W[(size_t)(k0 + r) * VOCAB + n0 + c4 + 1];
            if (n0 + c4 + 2 < VOCAB) v.z = W[(size_t)(k0 + r) * VOCAB + n0 + c4 + 2];
        }
        T[r][c4 + 0] = v.x; T[r][c4 + 1] = v.y; T[r][c4 + 2] = v.z; T[r][c4 + 3] = v.w;
    }
    __syncthreads();
    {
        int rn = tid >> 3, c4 = (tid & 7) * 4;
        if (n0 + rn < VOCAB) {
            ushort4 u;
            u.x = f2bfu(T[c4 + 0][rn]);
            u.y = f2bfu(T[c4 + 1][rn]);
            u.z = f2bfu(T[c4 + 2][rn]);
            u.w = f2bfu(T[c4 + 3][rn]);
            *(ushort4*)&wT[(size_t)(n0 + rn) * 512 + k0 + c4] = u;
        }
    }
}

// =====================================================================
// MFMA bf16 logits. grid 2000 1-D, XCD-pinned n-tiles, nt-stores for out.
// =====================================================================
__global__ __launch_bounds__(256) void k_logits(const unsigned short* __restrict__ A,
                                                const unsigned short* __restrict__ Bt,
                                                const float* __restrict__ bias,
                                                float* __restrict__ out)
{
    __shared__ unsigned short As16[128][40];
    __shared__ unsigned short Bs16[128][40];
    const int tid = threadIdx.x;
    const int lane = tid & 63, w = tid >> 6;
    const int quad = lane >> 4, l15 = lane & 15;
    const int bid = blockIdx.x;
    const int xcd = bid & 7;
    const int rest = bid >> 3;              // 0..249
    const int mb = rest % 25;
    const int nb = (rest / 25) * 8 + xcd;   // 0..79
    if (nb >= 79) return;
    const int n0 = nb * 128, m0 = mb * 128;

    f32x4 acc[8][2];
    #pragma unroll
    for (int i = 0; i < 8; ++i)
        #pragma unroll
        for (int j = 0; j < 2; ++j) acc[i][j] = (f32x4){0.f, 0.f, 0.f, 0.f};

    ushort4 pa[4], pb[4];
    #pragma unroll
    for (int l = 0; l < 4; ++l) {
        int idx = tid + l * 256;
        int r = idx >> 3, c8 = (idx & 7) * 4;
        pa[l] = *(const ushort4*)&A[(size_t)(m0 + r) * 512 + c8];
        ushort4 bv = {0, 0, 0, 0};
        if (n0 + r < VOCAB)
            bv = *(const ushort4*)&Bt[(size_t)(n0 + r) * 512 + c8];
        pb[l] = bv;
    }

    for (int k0 = 0; k0 < 512; k0 += 32) {
        #pragma unroll
        for (int l = 0; l < 4; ++l) {
            int idx = tid + l * 256;
            int r = idx >> 3, c8 = (idx & 7) * 4;
            *(ushort4*)&As16[r][c8] = pa[l];
            *(ushort4*)&Bs16[r][c8] = pb[l];
        }
        if (k0 + 32 < 512) {
            #pragma unroll
            for (int l = 0; l < 4; ++l) {
                int idx = tid + l * 256;
                int r = idx >> 3, c8 = (idx & 7) * 4;
                pa[l] = *(const ushort4*)&A[(size_t)(m0 + r) * 512 + k0 + 32 + c8];
                ushort4 bv = {0, 0, 0, 0};
                if (n0 + r < VOCAB)
                    bv = *(const ushort4*)&Bt[(size_t)(n0 + r) * 512 + k0 + 32 + c8];
                pb[l] = bv;
            }
        }
        __syncthreads();
        bf16x8 bfrag[2];
        #pragma unroll
        for (int nt = 0; nt < 2; ++nt)
            bfrag[nt] = *(const bf16x8*)&Bs16[w * 32 + nt * 16 + l15][quad * 8];
        #pragma unroll
        for (int mt = 0; mt < 8; ++mt) {
            bf16x8 afrag = *(const bf16x8*)&As16[mt * 16 + l15][quad * 8];
            acc[mt][0] = __builtin_amdgcn_mfma_f32_16x16x32_bf16(afrag, bfrag[0], acc[mt][0], 0, 0, 0);
            acc[mt][1] = __builtin_amdgcn_mfma_f32_16x16x32_bf16(afrag, bfrag[1], acc[mt][1], 0, 0, 0);
        }
        __syncthreads();
    }

    #pragma unroll
    for (int nt = 0; nt < 2; ++nt) {
        int n = n0 + w * 32 + nt * 16 + l15;
        if (n < VOCAB) {
            float bo = bias[n];
            #pragma unroll
            for (int mt = 0; mt < 8; ++mt) {
                #pragma unroll
                for (int r = 0; r < 4; ++r) {
                    int m = m0 + mt * 16 + quad * 4 + r;
                    int tt = m >> 7, bb = m & 127;
                    __builtin_nontemporal_store(acc[mt][nt][r] + bo,
                        &out[(size_t)bb * (TT * VOCAB) + (size_t)tt * VOCAB + n]);
                }
            }
        }
    }
}

extern "C" void kernel_launch(void* const* d_in, const int* in_sizes, int n_in,
                              void* d_out, int out_size, void* d_ws, size_t ws_size,
                              hipStream_t stream)
{
    const float* vgg  = (const float*)d_in[0];
    const int*   toks = (const int*)d_in[1];
    const float* emb  = (const float*)d_in[3];
    const float* Win  = (const float*)d_in[4];
    const float* bin  = (const float*)d_in[5];
    const float* Wu0  = (const float*)d_in[6];
    const float* bu0  = (const float*)d_in[7];
    const float* Wr0  = (const float*)d_in[8];
    const float* br0  = (const float*)d_in[9];
    const float* Wc0  = (const float*)d_in[10];
    const float* bc0  = (const float*)d_in[11];
    const float* Wu1  = (const float*)d_in[12];
    const float* bu1  = (const float*)d_in[13];
    const float* Wr1  = (const float*)d_in[14];
    const float* br1  = (const float*)d_in[15];
    const float* Wc1  = (const float*)d_in[16];
    const float* bc1  = (const float*)d_in[17];
    const float* Wout = (const float*)d_in[18];
    const float* bout = (const float*)d_in[19];

    const size_t S = (size_t)BB * HIDD;      // 65536 floats
    float* ws = (float*)d_ws;
    float* h0b[2] = {ws,         ws + S};
    float* h1b[2] = {ws + 2 * S, ws + 3 * S};
    float* gu0  = ws + 4 * S;
    float* grh0 = ws + 5 * S;
    float* gu1  = ws + 6 * S;
    float* grh1 = ws + 7 * S;
    // gu0..grh1 (4x 128*512) double as the h0 partial buffer pre-loop
    unsigned short* s1bf = (unsigned short*)(ws + 8 * S);     // TT*128*512 bf16
    unsigned short* wT   = s1bf + (size_t)TT * BB * HIDD;     // 10000*512 bf16
    unsigned short* xbf  = wT + (size_t)VOCAB * HIDD;         // 3200*512 bf16
    unsigned short* wxT  = xbf + (size_t)TT * BB * HIDD;      // 1536*512 bf16
    float* pre = (float*)(wxT + (size_t)1536 * HIDD);         // 3200*1536 fp32

    float* out = (float*)d_out;
    float* outS = out + (size_t)TT * BB * VOCAB;              // [2][128][512]

    k_wT<<<dim3(313, 16), 256, 0, stream>>>(Wout, wT);
    k_h0p<<<dim3(8, 64, 4), 256, 0, stream>>>(vgg, Win, gu0);
    k_h0f<<<dim3(64), 256, 0, stream>>>(gu0, bin, h0b[1], h1b[1]);
    k_xbf<<<dim3(1600), 256, 0, stream>>>(toks, emb, xbf);
    k_wxT3<<<dim3(16, 16, 3), 256, 0, stream>>>(Wu0, Wr0, Wc0, wxT);
    k_pre<<<dim3(12, 25), 256, 0, stream>>>(xbf, wxT, pre);

    // Layer-pipelined recurrence: iteration i = L0 step t0=i and L1 step t1=i-1.
    for (int i = 0; i <= TT; ++i) {
        int doL0 = (i < TT), doL1 = (i >= 1);
        const float* h0p_ = h0b[(i + 1) & 1];   // h0_{i-1}
        float*       h0c_ = h0b[i & 1];         // h0_i
        const float* h1p_ = h1b[i & 1];         // h1_{i-2}
        float*       h1c_ = h1b[(i + 1) & 1];   // h1_{i-1}

        k_gates<<<dim3(512), 512, 0, stream>>>(h0p_, h1p_, pre, i,
                                               Wu0, bu0, Wr0, br0,
                                               Wu1, bu1, Wr1, br1,
                                               gu0, grh0, gu1, grh1,
                                               doL0, doL1);
        k_cand<<<dim3(256), 512, 0, stream>>>(h0p_, h1p_, h0c_, h1c_,
                                              pre, i, i - 1,
                                              Wc0, bc0, Wc1, bc1,
                                              gu0, grh0, gu1, grh1,
                                              s1bf, outS, doL0, doL1);
    }

    k_logits<<<dim3(2000), 256, 0, stream>>>(s1bf, wT, bout, out);
}

// Round 5
// 1104.442 us; speedup vs baseline: 1.4516x; 1.4516x over previous
//
#include <hip/hip_runtime.h>
#include <hip/hip_bf16.h>

#define BB 128
#define TT 25
#define VOCAB 10000
#define HIDD 512

typedef __hip_bfloat16 bf16;
typedef short bf16x8 __attribute__((ext_vector_type(8)));
typedef float f32x4 __attribute__((ext_vector_type(4)));

__device__ __forceinline__ float sigmoidf_(float x) { return 1.0f / (1.0f + __expf(-x)); }

__device__ __forceinline__ float4 f4_fma(float s, float4 w, float4 a) {
    a.x += s * w.x; a.y += s * w.y; a.z += s * w.z; a.w += s * w.w;
    return a;
}

__device__ __forceinline__ unsigned short f2bfu(float x) {
    bf16 h = __float2bfloat16(x);
    return *reinterpret_cast<unsigned short*>(&h);
}

// =====================================================================
// h0 path
// =====================================================================
__device__ __forceinline__ float4 core128(const float* __restrict__ Wp,
                                          const float* __restrict__ arow)
{
    float4 acc = {0.f, 0.f, 0.f, 0.f};
    #pragma unroll 2
    for (int k = 0; k < 128; k += 8) {
        float4 w[8];
        #pragma unroll
        for (int j = 0; j < 8; ++j)
            w[j] = *(const float4*)(Wp + (size_t)(k + j) * 512);
        #pragma unroll
        for (int j = 0; j < 8; ++j)
            acc = f4_fma(arow[k + j], w[j], acc);
    }
    return acc;
}

#define PHASE_REDUCE(SVAR) \
    __syncthreads(); \
    float4 SVAR; \
    if (tid < 32) { \
        SVAR = red[tid]; \
        _Pragma("unroll") \
        for (int j = 1; j < 8; ++j) { \
            float4 p = red[tid + 32 * j]; \
            SVAR.x += p.x; SVAR.y += p.y; SVAR.z += p.z; SVAR.w += p.w; \
        } \
    }

// vgg[128,4096] @ W_in[4096,512], K split over 4 blocks (z). grid (8,64,4)
__global__ __launch_bounds__(256) void k_h0p(const float* __restrict__ A,
                                             const float* __restrict__ W,
                                             float* __restrict__ partial)
{
    __shared__ float As2[2][1032];
    __shared__ float4 red[256];
    const int tid = threadIdx.x;
    const int n4 = tid & 15, mi = (tid >> 4) & 1, kh = tid >> 5;
    const int m0 = blockIdx.y * 2, col0 = blockIdx.x * 64, kq = blockIdx.z;

    #pragma unroll
    for (int l = 0; l < 2; ++l) {
        int idx = tid + l * 256;
        int r = idx >> 8, c4 = (idx & 255) * 4;
        *(float4*)&As2[r][c4] =
            *(const float4*)&A[(size_t)(m0 + r) * 4096 + kq * 1024 + c4];
    }
    __syncthreads();
    red[tid] = core128(W + (size_t)(kq * 1024 + kh * 128) * 512 + col0 + n4 * 4,
                       &As2[mi][kh * 128]);
    PHASE_REDUCE(s)
    if (tid < 32) {
        int m = m0 + (tid >> 4), cc = col0 + (tid & 15) * 4;
        *(float4*)&partial[((size_t)kq * 128 + m) * 512 + cc] = s;
    }
}

// finalize: sum 4 partials + bias, tanh, write row-major h0/h1
__global__ void k_h0f(const float* __restrict__ partial,
                      const float* __restrict__ bias,
                      float* __restrict__ s0, float* __restrict__ s1)
{
    int i = blockIdx.x * 256 + threadIdx.x;
    size_t e = (size_t)i * 4;
    int cc = (int)(e & 511);
    float4 s = *(const float4*)&partial[e];
    #pragma unroll
    for (int j = 1; j < 4; ++j) {
        float4 p = *(const float4*)&partial[(size_t)j * 128 * 512 + e];
        s.x += p.x; s.y += p.y; s.z += p.z; s.w += p.w;
    }
    float4 b4 = *(const float4*)&bias[cc];
    float4 o;
    o.x = tanhf(s.x + b4.x); o.y = tanhf(s.y + b4.y);
    o.z = tanhf(s.z + b4.z); o.w = tanhf(s.w + b4.w);
    *(float4*)&s0[e] = o;
    *(float4*)&s1[e] = o;
}

// =====================================================================
// x-projection precompute (validated in round 4)
// =====================================================================
__global__ __launch_bounds__(256) void k_xbf(const int* __restrict__ toks,
                                             const float* __restrict__ emb,
                                             unsigned short* __restrict__ xbf)
{
    int i = (blockIdx.x * 256 + threadIdx.x) * 4;   // over 3200*512
    int row = i >> 9, col = i & 511;
    int b = row & 127, tt = row >> 7;
    int tok = toks[b * TT + tt];
    float4 v = *(const float4*)&emb[(size_t)tok * 512 + col];
    ushort4 u;
    u.x = f2bfu(v.x); u.y = f2bfu(v.y); u.z = f2bfu(v.z); u.w = f2bfu(v.w);
    *(ushort4*)&xbf[(size_t)row * 512 + col] = u;
}

// x-half (rows 0..511) of Wu0/Wr0/Wc0 -> transposed bf16 wxT[1536][512]
__global__ __launch_bounds__(256) void k_wxT3(const float* __restrict__ Wu,
                                              const float* __restrict__ Wr,
                                              const float* __restrict__ Wc,
                                              unsigned short* __restrict__ wxT)
{
    __shared__ float T[32][33];
    const int tid = threadIdx.x;
    const int n0 = blockIdx.x * 32, k0 = blockIdx.y * 32, g = blockIdx.z;
    const float* W = g == 0 ? Wu : g == 1 ? Wr : Wc;
    {
        int r = tid >> 3, c4 = (tid & 7) * 4;
        float4 v = *(const float4*)&W[(size_t)(k0 + r) * 512 + n0 + c4];
        T[r][c4 + 0] = v.x; T[r][c4 + 1] = v.y; T[r][c4 + 2] = v.z; T[r][c4 + 3] = v.w;
    }
    __syncthreads();
    {
        int rn = tid >> 3, c4 = (tid & 7) * 4;
        ushort4 u;
        u.x = f2bfu(T[c4 + 0][rn]);
        u.y = f2bfu(T[c4 + 1][rn]);
        u.z = f2bfu(T[c4 + 2][rn]);
        u.w = f2bfu(T[c4 + 3][rn]);
        *(ushort4*)&wxT[(size_t)(g * 512 + n0 + rn) * 512 + k0 + c4] = u;
    }
}

// pre[3200][1536] = xbf @ wxT^T  (MFMA bf16, fp32 out). grid (12, 25)
__global__ __launch_bounds__(256) void k_pre(const unsigned short* __restrict__ A,
                                             const unsigned short* __restrict__ Bt,
                                             float* __restrict__ out)
{
    __shared__ unsigned short As16[128][40];
    __shared__ unsigned short Bs16[128][40];
    const int tid = threadIdx.x;
    const int lane = tid & 63, w = tid >> 6;
    const int quad = lane >> 4, l15 = lane & 15;
    const int n0 = blockIdx.x * 128, m0 = blockIdx.y * 128;

    f32x4 acc[8][2];
    #pragma unroll
    for (int i = 0; i < 8; ++i)
        #pragma unroll
        for (int j = 0; j < 2; ++j) acc[i][j] = (f32x4){0.f, 0.f, 0.f, 0.f};

    ushort4 pa[4], pb[4];
    #pragma unroll
    for (int l = 0; l < 4; ++l) {
        int idx = tid + l * 256;
        int r = idx >> 3, c8 = (idx & 7) * 4;
        pa[l] = *(const ushort4*)&A[(size_t)(m0 + r) * 512 + c8];
        pb[l] = *(const ushort4*)&Bt[(size_t)(n0 + r) * 512 + c8];
    }

    for (int k0 = 0; k0 < 512; k0 += 32) {
        #pragma unroll
        for (int l = 0; l < 4; ++l) {
            int idx = tid + l * 256;
            int r = idx >> 3, c8 = (idx & 7) * 4;
            *(ushort4*)&As16[r][c8] = pa[l];
            *(ushort4*)&Bs16[r][c8] = pb[l];
        }
        if (k0 + 32 < 512) {
            #pragma unroll
            for (int l = 0; l < 4; ++l) {
                int idx = tid + l * 256;
                int r = idx >> 3, c8 = (idx & 7) * 4;
                pa[l] = *(const ushort4*)&A[(size_t)(m0 + r) * 512 + k0 + 32 + c8];
                pb[l] = *(const ushort4*)&Bt[(size_t)(n0 + r) * 512 + k0 + 32 + c8];
            }
        }
        __syncthreads();
        bf16x8 bfrag[2];
        #pragma unroll
        for (int nt = 0; nt < 2; ++nt)
            bfrag[nt] = *(const bf16x8*)&Bs16[w * 32 + nt * 16 + l15][quad * 8];
        #pragma unroll
        for (int mt = 0; mt < 8; ++mt) {
            bf16x8 afrag = *(const bf16x8*)&As16[mt * 16 + l15][quad * 8];
            acc[mt][0] = __builtin_amdgcn_mfma_f32_16x16x32_bf16(afrag, bfrag[0], acc[mt][0], 0, 0, 0);
            acc[mt][1] = __builtin_amdgcn_mfma_f32_16x16x32_bf16(afrag, bfrag[1], acc[mt][1], 0, 0, 0);
        }
        __syncthreads();
    }

    #pragma unroll
    for (int nt = 0; nt < 2; ++nt) {
        int n = n0 + w * 32 + nt * 16 + l15;
        #pragma unroll
        for (int mt = 0; mt < 8; ++mt) {
            #pragma unroll
            for (int r = 0; r < 4; ++r) {
                int m = m0 + mt * 16 + quad * 4 + r;
                out[(size_t)m * 1536 + n] = acc[mt][nt][r];
            }
        }
    }
}

// =====================================================================
// Gates kernel. grid 512 x 512thr. bx = mb(4b) | gate(2b) | cb(3b); XCD=cb.
// R3-proven lane layout: n4 = lane&15 (16 col4-groups, 256 B unique per
// W-load instr), rl = lane>>4 (4 rows), 2 acc sets (rows rl, rl+4) so the
// weight tile is read exactly once per block. LDS A-reads are 16-lane
// same-address broadcasts (free).
// L0 gates (gu0,gr0): K=512 (h-half; x-part folded from pre[]). L1: K=1024.
// gr gates store gr*h. All buffers row-major [128][512].
// =====================================================================
__global__ __launch_bounds__(512, 4) void k_gates(
    const float* __restrict__ h0p, const float* __restrict__ h1p,
    const float* __restrict__ pre, int t,
    const float* __restrict__ Wu0, const float* __restrict__ bu0,
    const float* __restrict__ Wr0, const float* __restrict__ br0,
    const float* __restrict__ Wu1, const float* __restrict__ bu1,
    const float* __restrict__ Wr1, const float* __restrict__ br1,
    float* __restrict__ gu0, float* __restrict__ grh0,
    float* __restrict__ gu1, float* __restrict__ grh1,
    int doL0, int doL1)
{
    __shared__ float As[8 * 1028];
    __shared__ float4 red[8][8][16];
    const int bx = blockIdx.x;
    const int cb = bx & 7, gate = (bx >> 3) & 3, mb = bx >> 5;
    if (gate < 2) { if (!doL0) return; } else { if (!doL1) return; }
    const int col0 = cb * 64, m0 = mb * 8;
    const int tid = threadIdx.x;
    const int L0 = gate < 2;

    if (L0) {
        #pragma unroll
        for (int l = 0; l < 2; ++l) {
            int idx = tid + l * 512;
            int r = idx >> 7, c4 = (idx & 127) * 4;
            *(float4*)&As[r * 1028 + c4] =
                *(const float4*)&h0p[(size_t)(m0 + r) * 512 + c4];
        }
    } else {
        #pragma unroll
        for (int l = 0; l < 4; ++l) {
            int idx = tid + l * 512;
            int r2 = idx >> 7, c4 = (idx & 127) * 4;
            int r = r2 & 7, half = r2 >> 3;
            const float* src = half ? h1p : h0p;
            *(float4*)&As[r * 1028 + half * 512 + c4] =
                *(const float4*)&src[(size_t)(m0 + r) * 512 + c4];
        }
    }
    __syncthreads();

    {
        const int kq = tid >> 6, lane = tid & 63;
        const int n4 = lane & 15, rl = lane >> 4;
        const int col = col0 + n4 * 4;
        const int Kw = L0 ? 64 : 128;
        const int nj = Kw >> 2;
        const float* W = gate == 0 ? Wu0 : gate == 1 ? Wr0 : gate == 2 ? Wu1 : Wr1;
        const int wrow0 = (L0 ? 512 : 0) + kq * Kw;
        const float* wp = W + (size_t)wrow0 * 512 + col;
        const float* ap0 = As + rl * 1028 + kq * Kw;
        const float* ap1 = As + (rl + 4) * 1028 + kq * Kw;
        float4 acc0a = {0.f,0.f,0.f,0.f}, acc0b = {0.f,0.f,0.f,0.f};
        float4 acc1a = {0.f,0.f,0.f,0.f}, acc1b = {0.f,0.f,0.f,0.f};
        #pragma unroll 4
        for (int j = 0; j < nj; ++j) {
            float4 a0 = *(const float4*)(ap0 + j * 4);
            float4 a1 = *(const float4*)(ap1 + j * 4);
            float4 w0 = *(const float4*)(wp + (size_t)(j * 4 + 0) * 512);
            float4 w1 = *(const float4*)(wp + (size_t)(j * 4 + 1) * 512);
            float4 w2 = *(const float4*)(wp + (size_t)(j * 4 + 2) * 512);
            float4 w3 = *(const float4*)(wp + (size_t)(j * 4 + 3) * 512);
            acc0a = f4_fma(a0.x, w0, acc0a); acc1a = f4_fma(a1.x, w0, acc1a);
            acc0b = f4_fma(a0.y, w1, acc0b); acc1b = f4_fma(a1.y, w1, acc1b);
            acc0a = f4_fma(a0.z, w2, acc0a); acc1a = f4_fma(a1.z, w2, acc1a);
            acc0b = f4_fma(a0.w, w3, acc0b); acc1b = f4_fma(a1.w, w3, acc1b);
        }
        float4 s0v, s1v;
        s0v.x = acc0a.x + acc0b.x; s0v.y = acc0a.y + acc0b.y;
        s0v.z = acc0a.z + acc0b.z; s0v.w = acc0a.w + acc0b.w;
        s1v.x = acc1a.x + acc1b.x; s1v.y = acc1a.y + acc1b.y;
        s1v.z = acc1a.z + acc1b.z; s1v.w = acc1a.w + acc1b.w;
        red[kq][rl][n4] = s0v;
        red[kq][rl + 4][n4] = s1v;
    }
    __syncthreads();

    if (tid < 128) {
        const int row = tid >> 4, n4 = tid & 15;
        float4 s = red[0][row][n4];
        #pragma unroll
        for (int kq = 1; kq < 8; ++kq) {
            float4 p = red[kq][row][n4];
            s.x += p.x; s.y += p.y; s.z += p.z; s.w += p.w;
        }
        const int col = col0 + n4 * 4;
        const int m = m0 + row;
        if (L0) {
            float4 p4 = *(const float4*)&pre[((size_t)t * 128 + m) * 1536
                                             + gate * 512 + col];
            s.x += p4.x; s.y += p4.y; s.z += p4.z; s.w += p4.w;
        }
        const float* bias = gate == 0 ? bu0 : gate == 1 ? br0 : gate == 2 ? bu1 : br1;
        float4 b4 = *(const float4*)&bias[col];
        float4 o;
        o.x = sigmoidf_(s.x + b4.x); o.y = sigmoidf_(s.y + b4.y);
        o.z = sigmoidf_(s.z + b4.z); o.w = sigmoidf_(s.w + b4.w);
        size_t ofs = (size_t)m * 512 + col;
        if (gate == 1) {
            float4 h = *(const float4*)&h0p[ofs];
            o.x *= h.x; o.y *= h.y; o.z *= h.z; o.w *= h.w;
        } else if (gate == 3) {
            float4 h = *(const float4*)&h1p[ofs];
            o.x *= h.x; o.y *= h.y; o.z *= h.z; o.w *= h.w;
        }
        float* outp = gate == 0 ? gu0 : gate == 1 ? grh0 : gate == 2 ? gu1 : grh1;
        *(float4*)&outp[ofs] = o;
    }
}

// =====================================================================
// Cand+combine. grid 256 x 1024thr (16 waves = 4/SIMD for latency hiding).
// bx = mb(4b) | gate(1b) | cb(3b); XCD=cb. 16-way K-split; LDS reduce.
// L0: hh0 = tanh(pre_c[t0] + grh0@Wc0h + bc0); K=512 (Kw=32).
// L1: hh1 = tanh([h0p;grh1]@Wc1 + bc1); K=1024 (Kw=64).
// =====================================================================
__global__ __launch_bounds__(1024, 2) void k_cand(
    const float* __restrict__ h0p, const float* __restrict__ h1p,
    float* __restrict__ h0c, float* __restrict__ h1c,
    const float* __restrict__ pre, int t0, int t1,
    const float* __restrict__ Wc0, const float* __restrict__ bc0,
    const float* __restrict__ Wc1, const float* __restrict__ bc1,
    const float* __restrict__ gu0, const float* __restrict__ grh0,
    const float* __restrict__ gu1, const float* __restrict__ grh1,
    unsigned short* __restrict__ s1bf, float* __restrict__ outS,
    int doL0, int doL1)
{
    __shared__ float As[8 * 1028];
    __shared__ float4 red[16][8][16];
    const int bx = blockIdx.x;
    const int cb = bx & 7, gate = (bx >> 3) & 1, mb = bx >> 4;
    if (gate == 0) { if (!doL0) return; } else { if (!doL1) return; }
    const int col0 = cb * 64, m0 = mb * 8;
    const int tid = threadIdx.x;
    const int L0 = gate == 0;

    if (L0) {
        if (tid < 1024) {
            int r = tid >> 7, c4 = (tid & 127) * 4;
            *(float4*)&As[r * 1028 + c4] =
                *(const float4*)&grh0[(size_t)(m0 + r) * 512 + c4];
        }
    } else {
        #pragma unroll
        for (int l = 0; l < 2; ++l) {
            int idx = tid + l * 1024;
            int r2 = idx >> 7, c4 = (idx & 127) * 4;
            int r = r2 & 7, half = r2 >> 3;
            const float* src = half ? grh1 : h0p;
            *(float4*)&As[r * 1028 + half * 512 + c4] =
                *(const float4*)&src[(size_t)(m0 + r) * 512 + c4];
        }
    }
    __syncthreads();

    {
        const int kq = tid >> 6, lane = tid & 63;   // kq 0..15
        const int n4 = lane & 15, rl = lane >> 4;
        const int col = col0 + n4 * 4;
        const int Kw = L0 ? 32 : 64;
        const int nj = Kw >> 2;
        const float* W = L0 ? Wc0 : Wc1;
        const int wrow0 = (L0 ? 512 : 0) + kq * Kw;
        const float* wp = W + (size_t)wrow0 * 512 + col;
        const float* ap0 = As + rl * 1028 + kq * Kw;
        const float* ap1 = As + (rl + 4) * 1028 + kq * Kw;
        float4 acc0a = {0.f,0.f,0.f,0.f}, acc0b = {0.f,0.f,0.f,0.f};
        float4 acc1a = {0.f,0.f,0.f,0.f}, acc1b = {0.f,0.f,0.f,0.f};
        #pragma unroll 4
        for (int j = 0; j < nj; ++j) {
            float4 a0 = *(const float4*)(ap0 + j * 4);
            float4 a1 = *(const float4*)(ap1 + j * 4);
            float4 w0 = *(const float4*)(wp + (size_t)(j * 4 + 0) * 512);
            float4 w1 = *(const float4*)(wp + (size_t)(j * 4 + 1) * 512);
            float4 w2 = *(const float4*)(wp + (size_t)(j * 4 + 2) * 512);
            float4 w3 = *(const float4*)(wp + (size_t)(j * 4 + 3) * 512);
            acc0a = f4_fma(a0.x, w0, acc0a); acc1a = f4_fma(a1.x, w0, acc1a);
            acc0b = f4_fma(a0.y, w1, acc0b); acc1b = f4_fma(a1.y, w1, acc1b);
            acc0a = f4_fma(a0.z, w2, acc0a); acc1a = f4_fma(a1.z, w2, acc1a);
            acc0b = f4_fma(a0.w, w3, acc0b); acc1b = f4_fma(a1.w, w3, acc1b);
        }
        float4 s0v, s1v;
        s0v.x = acc0a.x + acc0b.x; s0v.y = acc0a.y + acc0b.y;
        s0v.z = acc0a.z + acc0b.z; s0v.w = acc0a.w + acc0b.w;
        s1v.x = acc1a.x + acc1b.x; s1v.y = acc1a.y + acc1b.y;
        s1v.z = acc1a.z + acc1b.z; s1v.w = acc1a.w + acc1b.w;
        red[kq][rl][n4] = s0v;
        red[kq][rl + 4][n4] = s1v;
    }
    __syncthreads();

    if (tid < 128) {
        const int row = tid >> 4, n4 = tid & 15;
        float4 s = red[0][row][n4];
        #pragma unroll
        for (int kq = 1; kq < 16; ++kq) {
            float4 p = red[kq][row][n4];
            s.x += p.x; s.y += p.y; s.z += p.z; s.w += p.w;
        }
        const int col = col0 + n4 * 4;
        const int m = m0 + row;
        if (L0) {
            float4 p4 = *(const float4*)&pre[((size_t)t0 * 128 + m) * 1536
                                             + 1024 + col];
            s.x += p4.x; s.y += p4.y; s.z += p4.z; s.w += p4.w;
        }
        const float* bias = L0 ? bc0 : bc1;
        float4 b4 = *(const float4*)&bias[col];
        size_t ofs = (size_t)m * 512 + col;
        float4 g  = *(const float4*)&((L0 ? gu0 : gu1)[ofs]);
        float4 hv = *(const float4*)&((L0 ? h0p : h1p)[ofs]);
        float4 o;
        o.x = g.x * hv.x + (1.f - g.x) * tanhf(s.x + b4.x);
        o.y = g.y * hv.y + (1.f - g.y) * tanhf(s.y + b4.y);
        o.z = g.z * hv.z + (1.f - g.z) * tanhf(s.z + b4.z);
        o.w = g.w * hv.w + (1.f - g.w) * tanhf(s.w + b4.w);
        *(float4*)&((L0 ? h0c : h1c)[ofs]) = o;
        if (!L0) {
            ushort4 u;
            u.x = f2bfu(o.x); u.y = f2bfu(o.y); u.z = f2bfu(o.z); u.w = f2bfu(o.w);
            *(ushort4*)&s1bf[(size_t)t1 * BB * HIDD + ofs] = u;
            if (t1 == TT - 1)
                *(float4*)&outS[(size_t)BB * HIDD + ofs] = o;
        } else if (t0 == TT - 1) {
            *(float4*)&outS[ofs] = o;
        }
    }
}

// =====================================================================
// Wout transpose+convert: fp32 [512][10000] -> bf16 [10000][512].
// =====================================================================
__global__ __launch_bounds__(256) void k_wT(const float* __restrict__ W,
                                            unsigned short* __restrict__ wT)
{
    __shared__ float T[32][33];
    const int tid = threadIdx.x;
    const int n0 = blockIdx.x * 32, k0 = blockIdx.y * 32;
    {
        int r = tid >> 3, c4 = (tid & 7) * 4;
        float4 v = {0.f, 0.f, 0.f, 0.f};
        if (n0 + c4 + 3 < VOCAB)
            v = *(const float4*)&W[(size_t)(k0 + r) * VOCAB + n0 + c4];
        else {
            if (n0 + c4 + 0 < VOCAB) v.x = W[(size_t)(k0 + r) * VOCAB + n0 + c4 + 0];
            if (n0 + c4 + 1 < VOCAB) v.y = W[(size_t)(k0 + r) * VOCAB + n0 + c4 + 1];
            if (n0 + c4 + 2 < VOCAB) v.z = W[(size_t)(k0 + r) * VOCAB + n0 + c4 + 2];
        }
        T[r][c4 + 0] = v.x; T[r][c4 + 1] = v.y; T[r][c4 + 2] = v.z; T[r][c4 + 3] = v.w;
    }
    __syncthreads();
    {
        int rn = tid >> 3, c4 = (tid & 7) * 4;
        if (n0 + rn < VOCAB) {
            ushort4 u;
            u.x = f2bfu(T[c4 + 0][rn]);
            u.y = f2bfu(T[c4 + 1][rn]);
            u.z = f2bfu(T[c4 + 2][rn]);
            u.w = f2bfu(T[c4 + 3][rn]);
            *(ushort4*)&wT[(size_t)(n0 + rn) * 512 + k0 + c4] = u;
        }
    }
}

// =====================================================================
// MFMA bf16 logits. grid 2000 1-D, XCD-pinned n-tiles (round-3 proven).
// =====================================================================
__global__ __launch_bounds__(256) void k_logits(const unsigned short* __restrict__ A,
                                                const unsigned short* __restrict__ Bt,
                                                const float* __restrict__ bias,
                                                float* __restrict__ out)
{
    __shared__ unsigned short As16[128][40];
    __shared__ unsigned short Bs16[128][40];
    const int tid = threadIdx.x;
    const int lane = tid & 63, w = tid >> 6;
    const int quad = lane >> 4, l15 = lane & 15;
    const int bid = blockIdx.x;
    const int xcd = bid & 7;
    const int rest = bid >> 3;              // 0..249
    const int mb = rest % 25;
    const int nb = (rest / 25) * 8 + xcd;   // 0..79
    if (nb >= 79) return;
    const int n0 = nb * 128, m0 = mb * 128;

    f32x4 acc[8][2];
    #pragma unroll
    for (int i = 0; i < 8; ++i)
        #pragma unroll
        for (int j = 0; j < 2; ++j) acc[i][j] = (f32x4){0.f, 0.f, 0.f, 0.f};

    ushort4 pa[4], pb[4];
    #pragma unroll
    for (int l = 0; l < 4; ++l) {
        int idx = tid + l * 256;
        int r = idx >> 3, c8 = (idx & 7) * 4;
        pa[l] = *(const ushort4*)&A[(size_t)(m0 + r) * 512 + c8];
        ushort4 bv = {0, 0, 0, 0};
        if (n0 + r < VOCAB)
            bv = *(const ushort4*)&Bt[(size_t)(n0 + r) * 512 + c8];
        pb[l] = bv;
    }

    for (int k0 = 0; k0 < 512; k0 += 32) {
        #pragma unroll
        for (int l = 0; l < 4; ++l) {
            int idx = tid + l * 256;
            int r = idx >> 3, c8 = (idx & 7) * 4;
            *(ushort4*)&As16[r][c8] = pa[l];
            *(ushort4*)&Bs16[r][c8] = pb[l];
        }
        if (k0 + 32 < 512) {
            #pragma unroll
            for (int l = 0; l < 4; ++l) {
                int idx = tid + l * 256;
                int r = idx >> 3, c8 = (idx & 7) * 4;
                pa[l] = *(const ushort4*)&A[(size_t)(m0 + r) * 512 + k0 + 32 + c8];
                ushort4 bv = {0, 0, 0, 0};
                if (n0 + r < VOCAB)
                    bv = *(const ushort4*)&Bt[(size_t)(n0 + r) * 512 + k0 + 32 + c8];
                pb[l] = bv;
            }
        }
        __syncthreads();
        bf16x8 bfrag[2];
        #pragma unroll
        for (int nt = 0; nt < 2; ++nt)
            bfrag[nt] = *(const bf16x8*)&Bs16[w * 32 + nt * 16 + l15][quad * 8];
        #pragma unroll
        for (int mt = 0; mt < 8; ++mt) {
            bf16x8 afrag = *(const bf16x8*)&As16[mt * 16 + l15][quad * 8];
            acc[mt][0] = __builtin_amdgcn_mfma_f32_16x16x32_bf16(afrag, bfrag[0], acc[mt][0], 0, 0, 0);
            acc[mt][1] = __builtin_amdgcn_mfma_f32_16x16x32_bf16(afrag, bfrag[1], acc[mt][1], 0, 0, 0);
        }
        __syncthreads();
    }

    #pragma unroll
    for (int nt = 0; nt < 2; ++nt) {
        int n = n0 + w * 32 + nt * 16 + l15;
        if (n < VOCAB) {
            float bo = bias[n];
            #pragma unroll
            for (int mt = 0; mt < 8; ++mt) {
                #pragma unroll
                for (int r = 0; r < 4; ++r) {
                    int m = m0 + mt * 16 + quad * 4 + r;
                    int tt = m >> 7, bb = m & 127;
                    out[(size_t)bb * (TT * VOCAB) + (size_t)tt * VOCAB + n] =
                        acc[mt][nt][r] + bo;
                }
            }
        }
    }
}

extern "C" void kernel_launch(void* const* d_in, const int* in_sizes, int n_in,
                              void* d_out, int out_size, void* d_ws, size_t ws_size,
                              hipStream_t stream)
{
    const float* vgg  = (const float*)d_in[0];
    const int*   toks = (const int*)d_in[1];
    const float* emb  = (const float*)d_in[3];
    const float* Win  = (const float*)d_in[4];
    const float* bin  = (const float*)d_in[5];
    const float* Wu0  = (const float*)d_in[6];
    const float* bu0  = (const float*)d_in[7];
    const float* Wr0  = (const float*)d_in[8];
    const float* br0  = (const float*)d_in[9];
    const float* Wc0  = (const float*)d_in[10];
    const float* bc0  = (const float*)d_in[11];
    const float* Wu1  = (const float*)d_in[12];
    const float* bu1  = (const float*)d_in[13];
    const float* Wr1  = (const float*)d_in[14];
    const float* br1  = (const float*)d_in[15];
    const float* Wc1  = (const float*)d_in[16];
    const float* bc1  = (const float*)d_in[17];
    const float* Wout = (const float*)d_in[18];
    const float* bout = (const float*)d_in[19];

    const size_t S = (size_t)BB * HIDD;      // 65536 floats
    float* ws = (float*)d_ws;
    float* h0b[2] = {ws,         ws + S};
    float* h1b[2] = {ws + 2 * S, ws + 3 * S};
    float* gu0  = ws + 4 * S;
    float* grh0 = ws + 5 * S;
    float* gu1  = ws + 6 * S;
    float* grh1 = ws + 7 * S;
    // gu0..grh1 (4x 128*512) double as the h0 partial buffer pre-loop
    unsigned short* s1bf = (unsigned short*)(ws + 8 * S);     // TT*128*512 bf16
    unsigned short* wT   = s1bf + (size_t)TT * BB * HIDD;     // 10000*512 bf16
    unsigned short* xbf  = wT + (size_t)VOCAB * HIDD;         // 3200*512 bf16
    unsigned short* wxT  = xbf + (size_t)TT * BB * HIDD;      // 1536*512 bf16
    float* pre = (float*)(wxT + (size_t)1536 * HIDD);         // 3200*1536 fp32

    float* out = (float*)d_out;
    float* outS = out + (size_t)TT * BB * VOCAB;              // [2][128][512]

    k_wT<<<dim3(313, 16), 256, 0, stream>>>(Wout, wT);
    k_h0p<<<dim3(8, 64, 4), 256, 0, stream>>>(vgg, Win, gu0);
    k_h0f<<<dim3(64), 256, 0, stream>>>(gu0, bin, h0b[1], h1b[1]);
    k_xbf<<<dim3(1600), 256, 0, stream>>>(toks, emb, xbf);
    k_wxT3<<<dim3(16, 16, 3), 256, 0, stream>>>(Wu0, Wr0, Wc0, wxT);
    k_pre<<<dim3(12, 25), 256, 0, stream>>>(xbf, wxT, pre);

    // Layer-pipelined recurrence: iteration i = L0 step t0=i and L1 step t1=i-1.
    for (int i = 0; i <= TT; ++i) {
        int doL0 = (i < TT), doL1 = (i >= 1);
        const float* h0p_ = h0b[(i + 1) & 1];   // h0_{i-1}
        float*       h0c_ = h0b[i & 1];         // h0_i
        const float* h1p_ = h1b[i & 1];         // h1_{i-2}
        float*       h1c_ = h1b[(i + 1) & 1];   // h1_{i-1}

        k_gates<<<dim3(512), 512, 0, stream>>>(h0p_, h1p_, pre, i,
                                               Wu0, bu0, Wr0, br0,
                                               Wu1, bu1, Wr1, br1,
                                               gu0, grh0, gu1, grh1,
                                               doL0, doL1);
        k_cand<<<dim3(256), 1024, 0, stream>>>(h0p_, h1p_, h0c_, h1c_,
                                               pre, i, i - 1,
                                               Wc0, bc0, Wc1, bc1,
                                               gu0, grh0, gu1, grh1,
                                               s1bf, outS, doL0, doL1);
    }

    k_logits<<<dim3(2000), 256, 0, stream>>>(s1bf, wT, bout, out);
}